// Round 3
// baseline (356.798 us; speedup 1.0000x reference)
//
#include <hip/hip_runtime.h>
#include <float.h>

// VQ-VAE EMA vector quantizer, MI355X (gfx950).
// inputs:  [16,64,64,64] f32 (b,c,h,w) -> N=65536 positions, d=64
// embedding: [64,1024] f32 (d,K)
// outputs (flat, f32): q_st[4194304], loss[1], indices[65536],
//                      new_embedding[65536], new_cluster_size[1024], new_embed_avg[65536]
//
// Lessons: R7  — cooperative grid.sync ~30-40us each; separate launches win.
//          R8/R11 — score plateau ~127us (VALU-f32, LDS-operand-bound, 8 waves/CU).
//          R10 — cross-block ticket + device fences = 9x regression. Never.
//          R13 — bucket sizes are HEAVILY SKEWED: per-code work assignment
//                = 350-805us serial straggler. Balanced 32-sorted-entries/wave
//                + dwT atomics is the only dw structure that works.
// R14 == R9 exactly (proven 289us): 7 dispatches, 0 memsets.
// R17 (this): baseline counters (R16): score=130us, VALUBusy 75%, 42% of f32
//      FMA peak, LDS-instr-bound (8 waves x 4 ds_read_b128 = 384 LDS-cyc vs
//      256 FMA-cyc per CU per c). Retile score to 16x16/thread (256thr block
//      = 256pos x 256codes, kt=4): 8 reads per 256 FMA -> 0.5 B/FMA, LDS 384
//      < FMA 512 -> FMA-bound. ~330 VGPR, 1 wave/SIMD, LDS 129KB, 1 block/CU.
//      Strided float4 chunk ownership keeps b128 lane-stride 16B (no bank
//      conflicts). Per-(pos,code) FMA chain bitwise identical to R14 -> no
//      argmin-flip risk. Predict score ~70-80us, total ~235us.

#define K 1024
#define D 64
#define NPOS 65536
#define NELEM 4194304
#define DECAYF 0.99f
#define OMDF 0.01f
#define EPSF 1e-5f
#define CCOST 0.25f

#define OFF_Q 0
#define OFF_LOSS 4194304
#define OFF_IDX 4194305
#define OFF_EMB 4259841
#define OFF_NCS 4325377
#define OFF_AVG 4326401

// ws float layout:
// [0] loss | [64..1088) e2 | [1088..2112) cs | [2112..3136) cursor(int)
// [3136..4160) hist(int) | [4224..69760) idxi(int) | [69760..135296) perm(u32)
// [135296..266368) keys(u64 x 65536) | [266368..331904) dwT[K][64]
// [331904..397440) ET[K][64] | [397440..) xT[n][64] (optional, 16 MB)

// Tile-transpose E -> ET[K][64], fused e2; init keys/hist/loss/dwT (no memsets).
__global__ void __launch_bounds__(256) prep_kernel(
    const float* __restrict__ E, float* __restrict__ ET, float* __restrict__ e2,
    unsigned long long* __restrict__ keys, int* __restrict__ hist,
    float* __restrict__ loss, float* __restrict__ dwT) {
    __shared__ float tile[64][65];
    __shared__ float part[4][64];
    int tid = threadIdx.x;
    int gid = blockIdx.x * 256 + tid;  // 0..4095
#pragma unroll
    for (int i = 0; i < 16; ++i) keys[i * 4096 + gid] = ~0ull;
#pragma unroll
    for (int i = 0; i < 16; ++i) dwT[i * 4096 + gid] = 0.f;
    if (gid < K) hist[gid] = 0;
    if (gid == 0) *loss = 0.f;

    int k0 = blockIdx.x * 64;
    int kl = tid & 63;
    int cg_ = tid >> 6;  // 0..3
#pragma unroll
    for (int cc = 0; cc < 16; ++cc) {
        int c = cc * 4 + cg_;
        tile[c][kl] = E[c * K + k0 + kl];  // coalesced
    }
    __syncthreads();
    float s = 0.f;
#pragma unroll
    for (int i = 0; i < 16; ++i) {
        float v = tile[cg_ * 16 + i][kl];
        s = fmaf(v, v, s);
    }
    part[cg_][kl] = s;
#pragma unroll
    for (int i = 0; i < 16; ++i) {
        int w = i * 256 + tid;
        int k = w >> 6, c = w & 63;
        ET[(size_t)(k0 + k) * 64 + c] = tile[c][k];
    }
    __syncthreads();
    if (tid < 64) e2[k0 + tid] = part[0][tid] + part[1][tid] + part[2][tid] + part[3][tid];
}

__device__ __forceinline__ unsigned mono_f32(float s) {
    unsigned u = __float_as_uint(s);
    return (u & 0x80000000u) ? ~u : (u | 0x80000000u);
}

// R17: 16x16 per thread, 256pos x 256codes per block, grid (4 kt, 256 pt).
// Thread owns strided float4 chunks: codes {r*64 + tx*4 + jj}, pos {r*64 + ty*4 + ii}
// so each ds_read_b128 has 16B lane stride (conflict-free / broadcast).
__global__ void __launch_bounds__(256, 1) score_kernel(
    const float* __restrict__ in, const float* __restrict__ E,
    const float* __restrict__ e2, unsigned long long* __restrict__ keys) {
    __shared__ __align__(16) float xs[64 * 256];  // [c][pos]  64KB
    __shared__ __align__(16) float es[64 * 256];  // [c][code] 64KB
    __shared__ float e2s[256];
    unsigned long long* cand = (unsigned long long*)es;  // reuse after compute: [256 pos][stride 17]

    int tid = threadIdx.x;
    int kt = blockIdx.x;  // 0..3
    int pt = blockIdx.y;  // 0..255
    int n0 = pt * 256;
    int b = n0 >> 12;
    int r0 = n0 & 4095;

    {
        int p4 = (tid & 63) * 4;
        int c0 = tid >> 6;  // 0..3
#pragma unroll
        for (int cc = 0; cc < 64; cc += 4) {
            int c = cc + c0;
            *(float4*)(xs + c * 256 + p4) =
                *(const float4*)(in + (size_t)b * 262144 + c * 4096 + r0 + p4);
            *(float4*)(es + c * 256 + p4) =
                *(const float4*)(E + c * 1024 + kt * 256 + p4);
        }
        e2s[tid] = e2[kt * 256 + tid];
    }
    __syncthreads();

    int tx = tid & 15;
    int ty = tid >> 4;  // 0..15

    float acc[16][16];
#pragma unroll
    for (int i = 0; i < 16; ++i)
#pragma unroll
        for (int j = 0; j < 16; ++j) acc[i][j] = 0.f;

#pragma unroll 2
    for (int c = 0; c < 64; ++c) {
        float4 xa0 = *(float4*)(xs + c * 256 + 0 * 64 + ty * 4);
        float4 xa1 = *(float4*)(xs + c * 256 + 1 * 64 + ty * 4);
        float4 xa2 = *(float4*)(xs + c * 256 + 2 * 64 + ty * 4);
        float4 xa3 = *(float4*)(xs + c * 256 + 3 * 64 + ty * 4);
        float4 eb0 = *(float4*)(es + c * 256 + 0 * 64 + tx * 4);
        float4 eb1 = *(float4*)(es + c * 256 + 1 * 64 + tx * 4);
        float4 eb2 = *(float4*)(es + c * 256 + 2 * 64 + tx * 4);
        float4 eb3 = *(float4*)(es + c * 256 + 3 * 64 + tx * 4);
        float xv[16] = {xa0.x, xa0.y, xa0.z, xa0.w, xa1.x, xa1.y, xa1.z, xa1.w,
                        xa2.x, xa2.y, xa2.z, xa2.w, xa3.x, xa3.y, xa3.z, xa3.w};
        float ev[16] = {eb0.x, eb0.y, eb0.z, eb0.w, eb1.x, eb1.y, eb1.z, eb1.w,
                        eb2.x, eb2.y, eb2.z, eb2.w, eb3.x, eb3.y, eb3.z, eb3.w};
#pragma unroll
        for (int i = 0; i < 16; ++i)
#pragma unroll
            for (int j = 0; j < 16; ++j)
                acc[i][j] = fmaf(xv[i], ev[j], acc[i][j]);
    }
    __syncthreads();  // all waves done reading es before cand overwrites it

#pragma unroll
    for (int i = 0; i < 16; ++i) {
        float best = FLT_MAX;
        int bk = 0;
#pragma unroll
        for (int j = 0; j < 16; ++j) {
            int kl = (j >> 2) * 64 + tx * 4 + (j & 3);  // ascending k within thread
            float s = fmaf(-2.f, acc[i][j], e2s[kl]);
            if (s < best) { best = s; bk = kl; }  // strict <: first min wins
        }
        int pl = (i >> 2) * 64 + ty * 4 + (i & 3);
        unsigned long long cd =
            ((unsigned long long)mono_f32(best) << 32) | (unsigned)(kt * 256 + bk);
        cand[pl * 17 + tx] = cd;
    }
    __syncthreads();

    {
        unsigned long long bc = cand[tid * 17];
#pragma unroll
        for (int t = 1; t < 16; ++t) {
            unsigned long long v = cand[tid * 17 + t];
            if (v < bc) bc = v;
        }
        atomicMin(&keys[n0 + tid], bc);
    }
}

// 4 positions x 8 channels per thread; ET-based q gather; fused hist + idx.
__global__ void __launch_bounds__(256) finalize_kernel(
    const float* __restrict__ in, const float* __restrict__ ET,
    const unsigned long long* __restrict__ keys, float* __restrict__ out,
    int* __restrict__ idxi, float* __restrict__ xT, float* __restrict__ loss,
    int* __restrict__ hist) {
    int tid = threadIdx.x;
    int pg = tid & 31;
    int ch8 = tid >> 5;  // 0..7
    int np = blockIdx.x * 128 + pg * 4;
    int b = np >> 12, r = np & 4095;
    int c0 = ch8 * 8;
    const float* inb = in + (size_t)b * 262144 + r;
    float* qb = out + OFF_Q + (size_t)b * 262144 + r;

    int kk[4];
#pragma unroll
    for (int p = 0; p < 4; ++p) kk[p] = (int)(keys[np + p] & 0x3FFull);

    float4 xv[8];
#pragma unroll
    for (int i = 0; i < 8; ++i) xv[i] = *(const float4*)(inb + (c0 + i) * 4096);

    float4 e0[4], e1[4];
#pragma unroll
    for (int p = 0; p < 4; ++p) {
        const float* ep = ET + (size_t)kk[p] * 64 + c0;
        e0[p] = *(const float4*)ep;
        e1[p] = *(const float4*)(ep + 4);
    }

#define ECOMP(p, i) ((i) < 4 ? ((const float*)&e0[p])[(i)] : ((const float*)&e1[p])[(i) - 4])
#define XCOMP(i, p) ((p) == 0 ? xv[i].x : (p) == 1 ? xv[i].y : (p) == 2 ? xv[i].z : xv[i].w)

    float sq = 0.f;
#pragma unroll
    for (int i = 0; i < 8; ++i) {
        float4 qv = make_float4(ECOMP(0, i), ECOMP(1, i), ECOMP(2, i), ECOMP(3, i));
        *(float4*)(qb + (c0 + i) * 4096) = qv;
        float d0 = qv.x - xv[i].x, d1 = qv.y - xv[i].y;
        float d2 = qv.z - xv[i].z, d3 = qv.w - xv[i].w;
        sq = fmaf(d0, d0, sq); sq = fmaf(d1, d1, sq);
        sq = fmaf(d2, d2, sq); sq = fmaf(d3, d3, sq);
    }

    if (xT) {
#pragma unroll
        for (int p = 0; p < 4; ++p) {
            float* xp = xT + (size_t)(np + p) * 64 + c0;
            *(float4*)xp = make_float4(XCOMP(0, p), XCOMP(1, p), XCOMP(2, p), XCOMP(3, p));
            *(float4*)(xp + 4) = make_float4(XCOMP(4, p), XCOMP(5, p), XCOMP(6, p), XCOMP(7, p));
        }
    }

    if (ch8 == 0) {
#pragma unroll
        for (int p = 0; p < 4; ++p) out[OFF_IDX + np + p] = (float)kk[p];
        *(int4*)(idxi + np) = make_int4(kk[0], kk[1], kk[2], kk[3]);
#pragma unroll
        for (int p = 0; p < 4; ++p) atomicAdd(&hist[kk[p]], 1);
    }

#pragma unroll
    for (int off = 32; off > 0; off >>= 1) sq += __shfl_down(sq, off);
    if ((tid & 63) == 0) atomicAdd(loss, sq);
}

// One block: exclusive scan of hist + EMA stage1.
__global__ void __launch_bounds__(1024) scan_kernel(
    const int* __restrict__ hist, const float* __restrict__ cluster_size,
    const float* __restrict__ loss, float* __restrict__ out,
    float* __restrict__ cs_ws, int* __restrict__ cursor) {
    int t = threadIdx.x;
    __shared__ int sc[1024];
    __shared__ float fred[1024];
    int cnt = hist[t];
    sc[t] = cnt;
    __syncthreads();
    for (int off = 1; off < 1024; off <<= 1) {
        int v = (t >= off) ? sc[t - off] : 0;
        __syncthreads();
        sc[t] += v;
        __syncthreads();
    }
    cursor[t] = sc[t] - cnt;

    float ncs = cluster_size[t] * DECAYF + OMDF * (float)cnt;
    fred[t] = ncs;
    __syncthreads();
    for (int s = 512; s > 0; s >>= 1) {
        if (t < s) fred[t] += fred[t + s];
        __syncthreads();
    }
    float nsum = fred[0];
    out[OFF_NCS + t] = ncs;
    cs_ws[t] = (ncs + EPSF) / (nsum + 1024.f * EPSF) * nsum;
    if (t == 0) out[OFF_LOSS] = CCOST * loss[0] / (float)NELEM;
}

__global__ void __launch_bounds__(256) scatter_kernel(
    const int* __restrict__ idxi, int* __restrict__ cursor,
    unsigned* __restrict__ perm) {
    int n = blockIdx.x * 256 + threadIdx.x;
    int k = idxi[n];
    int slot = atomicAdd(&cursor[k], 1);
    perm[slot] = ((unsigned)k << 17) | (unsigned)n;  // k:10b, n:17b
}

// Balanced segmented reduction over sorted perm; wave = 32 entries.
// (R13 lesson: balance beats per-code — bucket skew makes per-code serial.)
__global__ void __launch_bounds__(256) dw_accum_kernel(
    const float* __restrict__ in, const float* __restrict__ xT,
    const unsigned* __restrict__ perm, float* __restrict__ dwT) {
    int t = threadIdx.x;
    int c = t & 63;
    int wv = t >> 6;
    int base = (blockIdx.x * 4 + wv) * 32;  // 2048 waves x 32 = 65536

    __shared__ unsigned spm[4][32];
    if (c < 32) spm[wv][c] = perm[base + c];
    __syncthreads();

    float acc = 0.f;
    unsigned cur = spm[wv][0] >> 17;
#pragma unroll 4
    for (int i = 0; i < 32; ++i) {
        unsigned e = spm[wv][i];  // broadcast
        unsigned k = e >> 17;
        unsigned n = e & 0x1FFFFu;
        if (k != cur) {  // wave-uniform
            atomicAdd(&dwT[cur * 64 + c], acc);
            acc = 0.f;
            cur = k;
        }
        if (xT) {
            acc += xT[(size_t)n * 64 + c];  // 256B contiguous per wave
        } else {
            acc += in[(size_t)(n >> 12) * 262144 + c * 4096 + (n & 4095)];
        }
    }
    atomicAdd(&dwT[cur * 64 + c], acc);
}

__global__ void __launch_bounds__(256) ema2_kernel(
    const float* __restrict__ embed_avg, const float* __restrict__ dwT,
    const float* __restrict__ cs_ws, float* __restrict__ out) {
    int i = blockIdx.x * 256 + threadIdx.x;  // i = c*K + k
    int k = i & (K - 1);
    int c = i >> 10;
    float avg = embed_avg[i] * DECAYF + OMDF * dwT[k * 64 + c];
    out[OFF_AVG + i] = avg;
    out[OFF_EMB + i] = avg / cs_ws[k];
}

extern "C" void kernel_launch(void* const* d_in, const int* in_sizes, int n_in,
                              void* d_out, int out_size, void* d_ws, size_t ws_size,
                              hipStream_t stream) {
    const float* in = (const float*)d_in[0];
    const float* E = (const float*)d_in[1];
    const float* cluster_size = (const float*)d_in[2];
    const float* embed_avg = (const float*)d_in[3];
    float* out = (float*)d_out;
    float* ws = (float*)d_ws;

    float* loss = ws;
    float* e2 = ws + 64;
    float* cs = ws + 1088;
    int* cursor = (int*)(ws + 2112);   // 1024
    int* hist = (int*)(ws + 3136);     // 1024
    int* idxi = (int*)(ws + 4224);     // 65536
    unsigned* perm = (unsigned*)(ws + 69760);  // 65536
    unsigned long long* keys = (unsigned long long*)(ws + 135296);  // 65536 u64
    float* dwT = ws + 266368;          // 65536 ([K][64])
    float* ET = ws + 331904;           // 65536 ([K][64])
    float* xT = (ws_size >= (397440ull + 4194304ull) * 4ull) ? (ws + 397440) : nullptr;

    prep_kernel<<<K / 64, 256, 0, stream>>>(E, ET, e2, keys, hist, loss, dwT);
    score_kernel<<<dim3(4, 256), 256, 0, stream>>>(in, E, e2, keys);
    finalize_kernel<<<NPOS / 128, 256, 0, stream>>>(in, ET, keys, out, idxi, xT, loss, hist);
    scan_kernel<<<1, 1024, 0, stream>>>(hist, cluster_size, loss, out, cs, cursor);
    scatter_kernel<<<NPOS / 256, 256, 0, stream>>>(idxi, cursor, perm);
    dw_accum_kernel<<<512, 256, 0, stream>>>(in, xT, perm, dwT);
    ema2_kernel<<<D * K / 256, 256, 0, stream>>>(embed_avg, dwT, cs, out);
}

// Round 5
// 296.002 us; speedup vs baseline: 1.2054x; 1.2054x over previous
//
#include <hip/hip_runtime.h>
#include <float.h>

// VQ-VAE EMA vector quantizer, MI355X (gfx950).
// inputs:  [16,64,64,64] f32 (b,c,h,w) -> N=65536 positions, d=64
// embedding: [64,1024] f32 (d,K)
//
// Lessons: R7  — cooperative grid.sync ~30-40us each; separate launches win.
//          R8/R11 — score plateau ~127us (VALU-f32, LDS-operand-bound).
//          R10 — cross-block ticket + device fences = 9x regression. Never.
//          R13 — bucket skew: per-code work = serial straggler. Balanced
//                32-sorted-entries/wave + dwT atomics only.
//          R14 == R9 (proven 289us total, score 130us @ 8x8/thread).
//          R17 — 16x16/thread FAILED: acc[256] spilled (VGPR_Count 164 < ~300
//                needed); VALUBusy 55% x 232us = 127us VALU = 2.3x FMA floor
//                (accvgpr/scratch shuffle tax). Max acc/thread ~128.
// R18: 8x16/thread, 512-thr block, 256pos x 256codes, kt=4.
//      Per CU per c: LDS 8w*6rd*12cy=576 vs FMA 8*128/2=512 (near-balanced;
//      R14 was 384/256). LDS bytes 4.3->3.2 GB. acc 128 + ops ~220 VGPR,
//      launch_bounds(512,2) caps 256 -> no spill. FMA chain per (pos,code)
//      bitwise-identical to R14. Predict score ~85us, total ~245us.
// R19: resubmit of R18 — R18's bench was an infra failure (container failed
//      twice, acquisition-level; no compile/launch happened). Theory untested.

#define K 1024
#define D 64
#define NPOS 65536
#define NELEM 4194304
#define DECAYF 0.99f
#define OMDF 0.01f
#define EPSF 1e-5f
#define CCOST 0.25f

#define OFF_Q 0
#define OFF_LOSS 4194304
#define OFF_IDX 4194305
#define OFF_EMB 4259841
#define OFF_NCS 4325377
#define OFF_AVG 4326401

// ws float layout:
// [0] loss | [64..1088) e2 | [1088..2112) cs | [2112..3136) cursor(int)
// [3136..4160) hist(int) | [4224..69760) idxi(int) | [69760..135296) perm(u32)
// [135296..266368) keys(u64 x 65536) | [266368..331904) dwT[K][64]
// [331904..397440) ET[K][64] | [397440..) xT[n][64] (optional, 16 MB)

// Tile-transpose E -> ET[K][64], fused e2; init keys/hist/loss/dwT (no memsets).
__global__ void __launch_bounds__(256) prep_kernel(
    const float* __restrict__ E, float* __restrict__ ET, float* __restrict__ e2,
    unsigned long long* __restrict__ keys, int* __restrict__ hist,
    float* __restrict__ loss, float* __restrict__ dwT) {
    __shared__ float tile[64][65];
    __shared__ float part[4][64];
    int tid = threadIdx.x;
    int gid = blockIdx.x * 256 + tid;  // 0..4095
#pragma unroll
    for (int i = 0; i < 16; ++i) keys[i * 4096 + gid] = ~0ull;
#pragma unroll
    for (int i = 0; i < 16; ++i) dwT[i * 4096 + gid] = 0.f;
    if (gid < K) hist[gid] = 0;
    if (gid == 0) *loss = 0.f;

    int k0 = blockIdx.x * 64;
    int kl = tid & 63;
    int cg_ = tid >> 6;  // 0..3
#pragma unroll
    for (int cc = 0; cc < 16; ++cc) {
        int c = cc * 4 + cg_;
        tile[c][kl] = E[c * K + k0 + kl];  // coalesced
    }
    __syncthreads();
    float s = 0.f;
#pragma unroll
    for (int i = 0; i < 16; ++i) {
        float v = tile[cg_ * 16 + i][kl];
        s = fmaf(v, v, s);
    }
    part[cg_][kl] = s;
#pragma unroll
    for (int i = 0; i < 16; ++i) {
        int w = i * 256 + tid;
        int k = w >> 6, c = w & 63;
        ET[(size_t)(k0 + k) * 64 + c] = tile[c][k];
    }
    __syncthreads();
    if (tid < 64) e2[k0 + tid] = part[0][tid] + part[1][tid] + part[2][tid] + part[3][tid];
}

__device__ __forceinline__ unsigned mono_f32(float s) {
    unsigned u = __float_as_uint(s);
    return (u & 0x80000000u) ? ~u : (u | 0x80000000u);
}

// R18: 8x16 per thread, 512 threads = 256 pos x 256 codes, grid (4 kt, 256 pt).
// pos chunks: {ty*4+ii, 128+ty*4+ii}; code chunks: {r*64 + tx*4 + jj}, r=0..3.
// All ds_read_b128 have 16B lane stride or 16-lane broadcast -> conflict-free.
__global__ void __launch_bounds__(512, 2) score_kernel(
    const float* __restrict__ in, const float* __restrict__ E,
    const float* __restrict__ e2, unsigned long long* __restrict__ keys) {
    __shared__ __align__(16) float xs[64 * 256];  // [c][pos]  64KB
    __shared__ __align__(16) float es[64 * 256];  // [c][code] 64KB
    __shared__ float e2s[256];
    unsigned long long* cand = (unsigned long long*)es;  // reuse: [256 pos][stride 17]

    int tid = threadIdx.x;
    int kt = blockIdx.x;  // 0..3
    int pt = blockIdx.y;  // 0..255
    int n0 = pt * 256;
    int b = n0 >> 12;
    int r0 = n0 & 4095;

    {
        int p4 = (tid & 63) * 4;
        int c0 = tid >> 6;  // 0..7
#pragma unroll
        for (int cc = 0; cc < 64; cc += 8) {
            int c = cc + c0;
            *(float4*)(xs + c * 256 + p4) =
                *(const float4*)(in + (size_t)b * 262144 + c * 4096 + r0 + p4);
            *(float4*)(es + c * 256 + p4) =
                *(const float4*)(E + c * 1024 + kt * 256 + p4);
        }
        if (tid < 256) e2s[tid] = e2[kt * 256 + tid];
    }
    __syncthreads();

    int tx = tid & 15;   // 16 code groups
    int ty = tid >> 4;   // 0..31 pos groups

    float acc[8][16];
#pragma unroll
    for (int i = 0; i < 8; ++i)
#pragma unroll
        for (int j = 0; j < 16; ++j) acc[i][j] = 0.f;

#pragma unroll 2
    for (int c = 0; c < 64; ++c) {
        float4 xa0 = *(float4*)(xs + c * 256 + ty * 4);
        float4 xa1 = *(float4*)(xs + c * 256 + 128 + ty * 4);
        float4 eb0 = *(float4*)(es + c * 256 + 0 * 64 + tx * 4);
        float4 eb1 = *(float4*)(es + c * 256 + 1 * 64 + tx * 4);
        float4 eb2 = *(float4*)(es + c * 256 + 2 * 64 + tx * 4);
        float4 eb3 = *(float4*)(es + c * 256 + 3 * 64 + tx * 4);
        float xv[8] = {xa0.x, xa0.y, xa0.z, xa0.w, xa1.x, xa1.y, xa1.z, xa1.w};
        float ev[16] = {eb0.x, eb0.y, eb0.z, eb0.w, eb1.x, eb1.y, eb1.z, eb1.w,
                        eb2.x, eb2.y, eb2.z, eb2.w, eb3.x, eb3.y, eb3.z, eb3.w};
#pragma unroll
        for (int i = 0; i < 8; ++i)
#pragma unroll
            for (int j = 0; j < 16; ++j)
                acc[i][j] = fmaf(xv[i], ev[j], acc[i][j]);
    }
    __syncthreads();  // all waves done reading es before cand overwrites it

#pragma unroll
    for (int i = 0; i < 8; ++i) {
        float best = FLT_MAX;
        int bk = 0;
#pragma unroll
        for (int j = 0; j < 16; ++j) {
            int kl = (j >> 2) * 64 + tx * 4 + (j & 3);  // ascending k within thread
            float s = fmaf(-2.f, acc[i][j], e2s[kl]);
            if (s < best) { best = s; bk = kl; }  // strict <: first min wins
        }
        int pl = (i < 4) ? (ty * 4 + i) : (128 + ty * 4 + (i - 4));
        unsigned long long cd =
            ((unsigned long long)mono_f32(best) << 32) | (unsigned)(kt * 256 + bk);
        cand[pl * 17 + tx] = cd;
    }
    __syncthreads();

    if (tid < 256) {
        unsigned long long bc = cand[tid * 17];
#pragma unroll
        for (int t = 1; t < 16; ++t) {
            unsigned long long v = cand[tid * 17 + t];
            if (v < bc) bc = v;
        }
        atomicMin(&keys[n0 + tid], bc);
    }
}

// 4 positions x 8 channels per thread; ET-based q gather; fused hist + idx.
__global__ void __launch_bounds__(256) finalize_kernel(
    const float* __restrict__ in, const float* __restrict__ ET,
    const unsigned long long* __restrict__ keys, float* __restrict__ out,
    int* __restrict__ idxi, float* __restrict__ xT, float* __restrict__ loss,
    int* __restrict__ hist) {
    int tid = threadIdx.x;
    int pg = tid & 31;
    int ch8 = tid >> 5;  // 0..7
    int np = blockIdx.x * 128 + pg * 4;
    int b = np >> 12, r = np & 4095;
    int c0 = ch8 * 8;
    const float* inb = in + (size_t)b * 262144 + r;
    float* qb = out + OFF_Q + (size_t)b * 262144 + r;

    int kk[4];
#pragma unroll
    for (int p = 0; p < 4; ++p) kk[p] = (int)(keys[np + p] & 0x3FFull);

    float4 xv[8];
#pragma unroll
    for (int i = 0; i < 8; ++i) xv[i] = *(const float4*)(inb + (c0 + i) * 4096);

    float4 e0[4], e1[4];
#pragma unroll
    for (int p = 0; p < 4; ++p) {
        const float* ep = ET + (size_t)kk[p] * 64 + c0;
        e0[p] = *(const float4*)ep;
        e1[p] = *(const float4*)(ep + 4);
    }

#define ECOMP(p, i) ((i) < 4 ? ((const float*)&e0[p])[(i)] : ((const float*)&e1[p])[(i) - 4])
#define XCOMP(i, p) ((p) == 0 ? xv[i].x : (p) == 1 ? xv[i].y : (p) == 2 ? xv[i].z : xv[i].w)

    float sq = 0.f;
#pragma unroll
    for (int i = 0; i < 8; ++i) {
        float4 qv = make_float4(ECOMP(0, i), ECOMP(1, i), ECOMP(2, i), ECOMP(3, i));
        *(float4*)(qb + (c0 + i) * 4096) = qv;
        float d0 = qv.x - xv[i].x, d1 = qv.y - xv[i].y;
        float d2 = qv.z - xv[i].z, d3 = qv.w - xv[i].w;
        sq = fmaf(d0, d0, sq); sq = fmaf(d1, d1, sq);
        sq = fmaf(d2, d2, sq); sq = fmaf(d3, d3, sq);
    }

    if (xT) {
#pragma unroll
        for (int p = 0; p < 4; ++p) {
            float* xp = xT + (size_t)(np + p) * 64 + c0;
            *(float4*)xp = make_float4(XCOMP(0, p), XCOMP(1, p), XCOMP(2, p), XCOMP(3, p));
            *(float4*)(xp + 4) = make_float4(XCOMP(4, p), XCOMP(5, p), XCOMP(6, p), XCOMP(7, p));
        }
    }

    if (ch8 == 0) {
#pragma unroll
        for (int p = 0; p < 4; ++p) out[OFF_IDX + np + p] = (float)kk[p];
        *(int4*)(idxi + np) = make_int4(kk[0], kk[1], kk[2], kk[3]);
#pragma unroll
        for (int p = 0; p < 4; ++p) atomicAdd(&hist[kk[p]], 1);
    }

#pragma unroll
    for (int off = 32; off > 0; off >>= 1) sq += __shfl_down(sq, off);
    if ((tid & 63) == 0) atomicAdd(loss, sq);
}

// One block: exclusive scan of hist + EMA stage1.
__global__ void __launch_bounds__(1024) scan_kernel(
    const int* __restrict__ hist, const float* __restrict__ cluster_size,
    const float* __restrict__ loss, float* __restrict__ out,
    float* __restrict__ cs_ws, int* __restrict__ cursor) {
    int t = threadIdx.x;
    __shared__ int sc[1024];
    __shared__ float fred[1024];
    int cnt = hist[t];
    sc[t] = cnt;
    __syncthreads();
    for (int off = 1; off < 1024; off <<= 1) {
        int v = (t >= off) ? sc[t - off] : 0;
        __syncthreads();
        sc[t] += v;
        __syncthreads();
    }
    cursor[t] = sc[t] - cnt;

    float ncs = cluster_size[t] * DECAYF + OMDF * (float)cnt;
    fred[t] = ncs;
    __syncthreads();
    for (int s = 512; s > 0; s >>= 1) {
        if (t < s) fred[t] += fred[t + s];
        __syncthreads();
    }
    float nsum = fred[0];
    out[OFF_NCS + t] = ncs;
    cs_ws[t] = (ncs + EPSF) / (nsum + 1024.f * EPSF) * nsum;
    if (t == 0) out[OFF_LOSS] = CCOST * loss[0] / (float)NELEM;
}

__global__ void __launch_bounds__(256) scatter_kernel(
    const int* __restrict__ idxi, int* __restrict__ cursor,
    unsigned* __restrict__ perm) {
    int n = blockIdx.x * 256 + threadIdx.x;
    int k = idxi[n];
    int slot = atomicAdd(&cursor[k], 1);
    perm[slot] = ((unsigned)k << 17) | (unsigned)n;  // k:10b, n:17b
}

// Balanced segmented reduction over sorted perm; wave = 32 entries.
// (R13 lesson: balance beats per-code — bucket skew makes per-code serial.)
__global__ void __launch_bounds__(256) dw_accum_kernel(
    const float* __restrict__ in, const float* __restrict__ xT,
    const unsigned* __restrict__ perm, float* __restrict__ dwT) {
    int t = threadIdx.x;
    int c = t & 63;
    int wv = t >> 6;
    int base = (blockIdx.x * 4 + wv) * 32;  // 2048 waves x 32 = 65536

    __shared__ unsigned spm[4][32];
    if (c < 32) spm[wv][c] = perm[base + c];
    __syncthreads();

    float acc = 0.f;
    unsigned cur = spm[wv][0] >> 17;
#pragma unroll 4
    for (int i = 0; i < 32; ++i) {
        unsigned e = spm[wv][i];  // broadcast
        unsigned k = e >> 17;
        unsigned n = e & 0x1FFFFu;
        if (k != cur) {  // wave-uniform
            atomicAdd(&dwT[cur * 64 + c], acc);
            acc = 0.f;
            cur = k;
        }
        if (xT) {
            acc += xT[(size_t)n * 64 + c];  // 256B contiguous per wave
        } else {
            acc += in[(size_t)(n >> 12) * 262144 + c * 4096 + (n & 4095)];
        }
    }
    atomicAdd(&dwT[cur * 64 + c], acc);
}

__global__ void __launch_bounds__(256) ema2_kernel(
    const float* __restrict__ embed_avg, const float* __restrict__ dwT,
    const float* __restrict__ cs_ws, float* __restrict__ out) {
    int i = blockIdx.x * 256 + threadIdx.x;  // i = c*K + k
    int k = i & (K - 1);
    int c = i >> 10;
    float avg = embed_avg[i] * DECAYF + OMDF * dwT[k * 64 + c];
    out[OFF_AVG + i] = avg;
    out[OFF_EMB + i] = avg / cs_ws[k];
}

extern "C" void kernel_launch(void* const* d_in, const int* in_sizes, int n_in,
                              void* d_out, int out_size, void* d_ws, size_t ws_size,
                              hipStream_t stream) {
    const float* in = (const float*)d_in[0];
    const float* E = (const float*)d_in[1];
    const float* cluster_size = (const float*)d_in[2];
    const float* embed_avg = (const float*)d_in[3];
    float* out = (float*)d_out;
    float* ws = (float*)d_ws;

    float* loss = ws;
    float* e2 = ws + 64;
    float* cs = ws + 1088;
    int* cursor = (int*)(ws + 2112);   // 1024
    int* hist = (int*)(ws + 3136);     // 1024
    int* idxi = (int*)(ws + 4224);     // 65536
    unsigned* perm = (unsigned*)(ws + 69760);  // 65536
    unsigned long long* keys = (unsigned long long*)(ws + 135296);  // 65536 u64
    float* dwT = ws + 266368;          // 65536 ([K][64])
    float* ET = ws + 331904;           // 65536 ([K][64])
    float* xT = (ws_size >= (397440ull + 4194304ull) * 4ull) ? (ws + 397440) : nullptr;

    prep_kernel<<<K / 64, 256, 0, stream>>>(E, ET, e2, keys, hist, loss, dwT);
    score_kernel<<<dim3(4, 256), 512, 0, stream>>>(in, E, e2, keys);
    finalize_kernel<<<NPOS / 128, 256, 0, stream>>>(in, ET, keys, out, idxi, xT, loss, hist);
    scan_kernel<<<1, 1024, 0, stream>>>(hist, cluster_size, loss, out, cs, cursor);
    scatter_kernel<<<NPOS / 256, 256, 0, stream>>>(idxi, cursor, perm);
    dw_accum_kernel<<<512, 256, 0, stream>>>(in, xT, perm, dwT);
    ema2_kernel<<<D * K / 256, 256, 0, stream>>>(embed_avg, dwT, cs, out);
}

// Round 7
// 242.230 us; speedup vs baseline: 1.4730x; 1.2220x over previous
//
#include <hip/hip_runtime.h>
#include <float.h>

// VQ-VAE EMA vector quantizer, MI355X (gfx950).
// inputs:  [16,64,64,64] f32 (b,c,h,w) -> N=65536 positions, d=64
// embedding: [64,1024] f32 (d,K)
//
// Lessons: R7  — cooperative grid.sync ~30-40us each; separate launches win.
//          R8/R11 — score plateau ~127us (VALU-f32, LDS-operand-bound).
//          R10 — cross-block ticket + device fences = 9x regression. Never.
//          R13 — bucket skew: per-code work = serial straggler. Balanced
//                32-sorted-entries/wave + dwT atomics only.
//          R14 == R9 (proven 289us total, score 130us @ 8x8/thread).
//          R17 — 16x16/thread: acc[256] spilled, 2.3x VALU tax. 232us.
//          R19 — 8x16/thread: VGPR_Count=108 -> acc in AGPRs again, 1.7x
//                VALU move tax, 131us == R14. f32-VALU score is
//                REGALLOC-WALLED at ~130us. Stop fighting the allocator.
// R20: MFMA f16 hi/lo (x=xh+xl, e=eh+el; 3 products, err<~1e-4) via
//      mfma_f32_16x16x16f16 (canonical CDNA layout: idx16=lane&15,
//      k=(lane>>4)*4+j; C/D row=(lane>>4)*4+reg, col=lane&15 [m89]).
//      Swapped operands: D[code][pos] = ET x X so lane's pos is FIXED ->
//      per-lane running (best,second,bk) across all 1024 codes in regs.
//      Track global runner-up; flag gap<DELTA=4e-3 (err bound << DELTA/2);
//      finalize recomputes flagged positions' argmin in EXACT f32 over all
//      1024 codes -> unflagged provably match f32 winner; flagged = f32
//      semantics. keys: plain store (no init/atomicMin).
// R21: R20 failed to COMPILE — legacy K=16 intrinsic is spelled
//      __builtin_amdgcn_mfma_f32_16x16x16f16 (no underscore) per clang's
//      own suggestion. One-token fix; theory untested until now.
//      Predict score 131 -> 20-30us, MfmaUtil>0, total ~185-215us.

#define K 1024
#define D 64
#define NPOS 65536
#define NELEM 4194304
#define DECAYF 0.99f
#define OMDF 0.01f
#define EPSF 1e-5f
#define CCOST 0.25f
#define DELTA 0.004f

#define OFF_Q 0
#define OFF_LOSS 4194304
#define OFF_IDX 4194305
#define OFF_EMB 4259841
#define OFF_NCS 4325377
#define OFF_AVG 4326401

typedef _Float16 half4 __attribute__((ext_vector_type(4)));
typedef float f32x4 __attribute__((ext_vector_type(4)));

// ws float layout:
// [0] loss | [64..1088) e2 | [1088..2112) cs | [2112..3136) cursor(int)
// [3136..4160) hist(int) | [4224..69760) idxi(int) | [69760..135296) perm(u32)
// [135296..266368) keys(u64 x 65536) | [266368..331904) dwT[K][64]
// [331904..397440) ET[K][64] | [397440..) xT[n][64] (optional, 16 MB)

// Tile-transpose E -> ET[K][64], fused e2; init hist/loss/dwT (no memsets).
__global__ void __launch_bounds__(256) prep_kernel(
    const float* __restrict__ E, float* __restrict__ ET, float* __restrict__ e2,
    int* __restrict__ hist, float* __restrict__ loss, float* __restrict__ dwT) {
    __shared__ float tile[64][65];
    __shared__ float part[4][64];
    int tid = threadIdx.x;
    int gid = blockIdx.x * 256 + tid;  // 0..4095
#pragma unroll
    for (int i = 0; i < 16; ++i) dwT[i * 4096 + gid] = 0.f;
    if (gid < K) hist[gid] = 0;
    if (gid == 0) *loss = 0.f;

    int k0 = blockIdx.x * 64;
    int kl = tid & 63;
    int cg_ = tid >> 6;  // 0..3
#pragma unroll
    for (int cc = 0; cc < 16; ++cc) {
        int c = cc * 4 + cg_;
        tile[c][kl] = E[c * K + k0 + kl];  // coalesced
    }
    __syncthreads();
    float s = 0.f;
#pragma unroll
    for (int i = 0; i < 16; ++i) {
        float v = tile[cg_ * 16 + i][kl];
        s = fmaf(v, v, s);
    }
    part[cg_][kl] = s;
#pragma unroll
    for (int i = 0; i < 16; ++i) {
        int w = i * 256 + tid;
        int k = w >> 6, c = w & 63;
        ET[(size_t)(k0 + k) * 64 + c] = tile[c][k];
    }
    __syncthreads();
    if (tid < 64) e2[k0 + tid] = part[0][tid] + part[1][tid] + part[2][tid] + part[3][tid];
}

__device__ __forceinline__ unsigned mono_f32(float s) {
    unsigned u = __float_as_uint(s);
    return (u & 0x80000000u) ? ~u : (u | 0x80000000u);
}

// R20 MFMA score: 512 thr = 8 waves (wp=pos-half 0..1, wc=code-quarter 0..3).
// Block = 128 pos x all 1024 codes (kt 0..3 x 256 codes staged per iter).
// Wave: 64 pos (4 col-tiles) x 256 codes. Lane: pos col = lane&15 fixed.
__global__ void __launch_bounds__(512, 2) score_kernel(
    const float* __restrict__ in, const float* __restrict__ ET,
    const float* __restrict__ e2, unsigned long long* __restrict__ keys) {
    __shared__ __align__(16) float xf[64 * 132];   // [chan][pos 128] padded
    __shared__ __align__(16) char sE[65536];       // frag-linear E f16 h/l, per kt
    __shared__ float e2s[1024];
    __shared__ float mgb[128][4];
    __shared__ int   mgi[128][4];
    __shared__ float mgs[128][4];

    int tid = threadIdx.x;
    int lane = tid & 63;
    int w = tid >> 6;
    int wp = w >> 2;   // 0..1
    int wc = w & 3;    // 0..3
    int g = lane >> 4; // 0..3
    int c16 = lane & 15;

    int n0 = blockIdx.x * 128;
    int b = n0 >> 12;
    int r0 = n0 & 4095;

    // stage x f32 tile [64 chan][128 pos]
#pragma unroll
    for (int it = 0; it < 4; ++it) {
        int idx = it * 512 + tid;   // 0..2047
        int c = idx >> 5;
        int q = idx & 31;
        float4 v = *(const float4*)(in + (size_t)b * 262144 + c * 4096 + r0 + q * 4);
        *(float4*)(&xf[c * 132 + q * 4]) = v;
    }
    e2s[tid] = e2[tid];
    e2s[512 + tid] = e2[512 + tid];
    __syncthreads();

    // persistent x fragments (B operand): B[k][col=pos], k=(lane>>4)*4+j+s*16
    half4 Bh[4][4], Bl[4][4];   // [pt][s]
#pragma unroll
    for (int pt = 0; pt < 4; ++pt) {
        int p = wp * 64 + pt * 16 + c16;
#pragma unroll
        for (int s = 0; s < 4; ++s) {
            half4 hh, ll;
#pragma unroll
            for (int j = 0; j < 4; ++j) {
                float v = xf[(g * 4 + j + s * 16) * 132 + p];
                _Float16 h = (_Float16)v;
                hh[j] = h;
                ll[j] = (_Float16)(v - (float)h);
            }
            Bh[pt][s] = hh; Bl[pt][s] = ll;
        }
    }

    float best[4], sec[4]; int bk[4];
#pragma unroll
    for (int pt = 0; pt < 4; ++pt) { best[pt] = FLT_MAX; sec[pt] = FLT_MAX; bk[pt] = 0; }

    for (int kt = 0; kt < 4; ++kt) {
        __syncthreads();  // previous kt's sE reads complete
        // stage E frags for codes kt*256..+256 (A operand, frag-linear h/l)
#pragma unroll
        for (int q8 = 0; q8 < 8; ++q8) {
            int id = q8 * 512 + tid;      // 0..4095
            int lane_ = id & 63;
            int s_ = (id >> 6) & 3;
            int grt = id >> 8;            // 0..15
            int code = kt * 256 + grt * 16 + (lane_ & 15);
            int chanb = ((lane_ >> 4) & 3) * 4 + s_ * 16;
            float4 ev = *(const float4*)(ET + (size_t)code * 64 + chanb);
            float fv[4] = {ev.x, ev.y, ev.z, ev.w};
            half4 hh, ll;
#pragma unroll
            for (int j = 0; j < 4; ++j) {
                _Float16 h = (_Float16)fv[j];
                hh[j] = h;
                ll[j] = (_Float16)(fv[j] - (float)h);
            }
            char* basep = sE + (size_t)((grt * 4 + s_) * 2) * 512 + lane_ * 8;
            *(half4*)basep = hh;
            *(half4*)(basep + 512) = ll;
        }
        __syncthreads();

#pragma unroll
        for (int rt = 0; rt < 4; ++rt) {
            int grt = wc * 4 + rt;
            f32x4 acc[4];
#pragma unroll
            for (int pt = 0; pt < 4; ++pt) acc[pt] = {0.f, 0.f, 0.f, 0.f};
#pragma unroll
            for (int s = 0; s < 4; ++s) {
                const char* eb = sE + (size_t)((grt * 4 + s) * 2) * 512 + lane * 8;
                half4 Ah = *(const half4*)eb;
                half4 Al = *(const half4*)(eb + 512);
#pragma unroll
                for (int pt = 0; pt < 4; ++pt)
                    acc[pt] = __builtin_amdgcn_mfma_f32_16x16x16f16(Ah, Bh[pt][s], acc[pt], 0, 0, 0);
#pragma unroll
                for (int pt = 0; pt < 4; ++pt)
                    acc[pt] = __builtin_amdgcn_mfma_f32_16x16x16f16(Ah, Bl[pt][s], acc[pt], 0, 0, 0);
#pragma unroll
                for (int pt = 0; pt < 4; ++pt)
                    acc[pt] = __builtin_amdgcn_mfma_f32_16x16x16f16(Al, Bh[pt][s], acc[pt], 0, 0, 0);
            }
            int cb = kt * 256 + grt * 16 + g * 4;
#pragma unroll
            for (int r = 0; r < 4; ++r) {
                float ev2 = e2s[cb + r];
                int code = cb + r;
#pragma unroll
                for (int pt = 0; pt < 4; ++pt) {
                    float sc = fmaf(-2.f, acc[pt][r], ev2);
                    if (sc < best[pt]) { sec[pt] = best[pt]; best[pt] = sc; bk[pt] = code; }
                    else sec[pt] = fminf(sec[pt], sc);
                }
            }
        }
    }

    // merge the 4 lane-groups (disjoint code ranges, same pos col)
#pragma unroll
    for (int pt = 0; pt < 4; ++pt) {
#pragma unroll
        for (int m = 16; m <= 32; m <<= 1) {
            float ob = __shfl_xor(best[pt], m);
            int obk = __shfl_xor(bk[pt], m);
            float os = __shfl_xor(sec[pt], m);
            bool take = (ob < best[pt]) || (ob == best[pt] && obk < bk[pt]);
            float ns = take ? fminf(os, best[pt]) : fminf(sec[pt], ob);
            best[pt] = take ? ob : best[pt];
            bk[pt] = take ? obk : bk[pt];
            sec[pt] = ns;
        }
        if (lane < 16) {
            int posl = wp * 64 + pt * 16 + lane;
            mgb[posl][wc] = best[pt]; mgi[posl][wc] = bk[pt]; mgs[posl][wc] = sec[pt];
        }
    }
    __syncthreads();
    if (tid < 128) {
        float bb = mgb[tid][0]; int kw = mgi[tid][0]; float ss = mgs[tid][0];
#pragma unroll
        for (int i = 1; i < 4; ++i) {
            float ob = mgb[tid][i]; int ok = mgi[tid][i]; float os = mgs[tid][i];
            bool take = (ob < bb) || (ob == bb && ok < kw);
            ss = take ? fminf(os, bb) : fminf(ss, ob);
            bb = take ? ob : bb;
            kw = take ? ok : kw;
        }
        unsigned flag = ((ss - bb) < DELTA) ? (1u << 16) : 0u;
        keys[n0 + tid] = ((unsigned long long)mono_f32(bb) << 32) | (unsigned)kw | flag;
    }
}

// finalize: fixup flagged positions (exact f32 argmin over all 1024 codes),
// then 4 pos x 8 chan per thread: q gather, loss, hist, idx, xT.
__global__ void __launch_bounds__(256) finalize_kernel(
    const float* __restrict__ in, const float* __restrict__ ET,
    const float* __restrict__ e2, const unsigned long long* __restrict__ keys,
    float* __restrict__ out, int* __restrict__ idxi, float* __restrict__ xT,
    float* __restrict__ loss, int* __restrict__ hist) {
    __shared__ int s_kk[128];
    __shared__ int s_fl[128];
    __shared__ int s_nf;
    __shared__ float s_x[64];
    __shared__ unsigned long long s_red[256];

    int tid = threadIdx.x;
    if (tid == 0) s_nf = 0;
    __syncthreads();
    if (tid < 128) {
        unsigned long long key = keys[blockIdx.x * 128 + tid];
        s_kk[tid] = (int)(key & 0x3FFull);
        if (key & (1ull << 16)) {
            int sl = atomicAdd(&s_nf, 1);
            s_fl[sl] = tid;
        }
    }
    __syncthreads();
    int nf = s_nf;
    for (int f = 0; f < nf; ++f) {
        int posl = s_fl[f];
        int n = blockIdx.x * 128 + posl;
        if (tid < 64) s_x[tid] = in[(size_t)(n >> 12) * 262144 + tid * 4096 + (n & 4095)];
        __syncthreads();
        unsigned long long bkey = ~0ull;
#pragma unroll
        for (int i = 0; i < 4; ++i) {
            int c = tid + i * 256;
            const float* ep = ET + (size_t)c * 64;
            float dot = 0.f;
#pragma unroll
            for (int j = 0; j < 64; ++j) dot = fmaf(s_x[j], ep[j], dot);
            float sc = fmaf(-2.f, dot, e2[c]);
            unsigned long long kq = ((unsigned long long)mono_f32(sc) << 32) | (unsigned)c;
            if (kq < bkey) bkey = kq;
        }
        s_red[tid] = bkey;
        __syncthreads();
        for (int off = 128; off > 0; off >>= 1) {
            if (tid < off) {
                unsigned long long o = s_red[tid + off];
                if (o < s_red[tid]) s_red[tid] = o;
            }
            __syncthreads();
        }
        if (tid == 0) s_kk[posl] = (int)(s_red[0] & 0x3FFull);
        __syncthreads();
    }

    int pg = tid & 31;
    int ch8 = tid >> 5;  // 0..7
    int np = blockIdx.x * 128 + pg * 4;
    int b = np >> 12, r = np & 4095;
    int c0 = ch8 * 8;
    const float* inb = in + (size_t)b * 262144 + r;
    float* qb = out + OFF_Q + (size_t)b * 262144 + r;

    int kk[4];
#pragma unroll
    for (int p = 0; p < 4; ++p) kk[p] = s_kk[pg * 4 + p];

    float4 xv[8];
#pragma unroll
    for (int i = 0; i < 8; ++i) xv[i] = *(const float4*)(inb + (c0 + i) * 4096);

    float4 e0[4], e1[4];
#pragma unroll
    for (int p = 0; p < 4; ++p) {
        const float* ep = ET + (size_t)kk[p] * 64 + c0;
        e0[p] = *(const float4*)ep;
        e1[p] = *(const float4*)(ep + 4);
    }

#define ECOMP(p, i) ((i) < 4 ? ((const float*)&e0[p])[(i)] : ((const float*)&e1[p])[(i) - 4])
#define XCOMP(i, p) ((p) == 0 ? xv[i].x : (p) == 1 ? xv[i].y : (p) == 2 ? xv[i].z : xv[i].w)

    float sq = 0.f;
#pragma unroll
    for (int i = 0; i < 8; ++i) {
        float4 qv = make_float4(ECOMP(0, i), ECOMP(1, i), ECOMP(2, i), ECOMP(3, i));
        *(float4*)(qb + (c0 + i) * 4096) = qv;
        float d0 = qv.x - xv[i].x, d1 = qv.y - xv[i].y;
        float d2 = qv.z - xv[i].z, d3 = qv.w - xv[i].w;
        sq = fmaf(d0, d0, sq); sq = fmaf(d1, d1, sq);
        sq = fmaf(d2, d2, sq); sq = fmaf(d3, d3, sq);
    }

    if (xT) {
#pragma unroll
        for (int p = 0; p < 4; ++p) {
            float* xp = xT + (size_t)(np + p) * 64 + c0;
            *(float4*)xp = make_float4(XCOMP(0, p), XCOMP(1, p), XCOMP(2, p), XCOMP(3, p));
            *(float4*)(xp + 4) = make_float4(XCOMP(4, p), XCOMP(5, p), XCOMP(6, p), XCOMP(7, p));
        }
    }

    if (ch8 == 0) {
#pragma unroll
        for (int p = 0; p < 4; ++p) out[OFF_IDX + np + p] = (float)kk[p];
        *(int4*)(idxi + np) = make_int4(kk[0], kk[1], kk[2], kk[3]);
#pragma unroll
        for (int p = 0; p < 4; ++p) atomicAdd(&hist[kk[p]], 1);
    }

#pragma unroll
    for (int off = 32; off > 0; off >>= 1) sq += __shfl_down(sq, off);
    if ((tid & 63) == 0) atomicAdd(loss, sq);
}

// One block: exclusive scan of hist + EMA stage1.
__global__ void __launch_bounds__(1024) scan_kernel(
    const int* __restrict__ hist, const float* __restrict__ cluster_size,
    const float* __restrict__ loss, float* __restrict__ out,
    float* __restrict__ cs_ws, int* __restrict__ cursor) {
    int t = threadIdx.x;
    __shared__ int sc[1024];
    __shared__ float fred[1024];
    int cnt = hist[t];
    sc[t] = cnt;
    __syncthreads();
    for (int off = 1; off < 1024; off <<= 1) {
        int v = (t >= off) ? sc[t - off] : 0;
        __syncthreads();
        sc[t] += v;
        __syncthreads();
    }
    cursor[t] = sc[t] - cnt;

    float ncs = cluster_size[t] * DECAYF + OMDF * (float)cnt;
    fred[t] = ncs;
    __syncthreads();
    for (int s = 512; s > 0; s >>= 1) {
        if (t < s) fred[t] += fred[t + s];
        __syncthreads();
    }
    float nsum = fred[0];
    out[OFF_NCS + t] = ncs;
    cs_ws[t] = (ncs + EPSF) / (nsum + 1024.f * EPSF) * nsum;
    if (t == 0) out[OFF_LOSS] = CCOST * loss[0] / (float)NELEM;
}

__global__ void __launch_bounds__(256) scatter_kernel(
    const int* __restrict__ idxi, int* __restrict__ cursor,
    unsigned* __restrict__ perm) {
    int n = blockIdx.x * 256 + threadIdx.x;
    int k = idxi[n];
    int slot = atomicAdd(&cursor[k], 1);
    perm[slot] = ((unsigned)k << 17) | (unsigned)n;  // k:10b, n:17b
}

// Balanced segmented reduction over sorted perm; wave = 32 entries.
__global__ void __launch_bounds__(256) dw_accum_kernel(
    const float* __restrict__ in, const float* __restrict__ xT,
    const unsigned* __restrict__ perm, float* __restrict__ dwT) {
    int t = threadIdx.x;
    int c = t & 63;
    int wv = t >> 6;
    int base = (blockIdx.x * 4 + wv) * 32;  // 2048 waves x 32 = 65536

    __shared__ unsigned spm[4][32];
    if (c < 32) spm[wv][c] = perm[base + c];
    __syncthreads();

    float acc = 0.f;
    unsigned cur = spm[wv][0] >> 17;
#pragma unroll 4
    for (int i = 0; i < 32; ++i) {
        unsigned e = spm[wv][i];  // broadcast
        unsigned k = e >> 17;
        unsigned n = e & 0x1FFFFu;
        if (k != cur) {  // wave-uniform
            atomicAdd(&dwT[cur * 64 + c], acc);
            acc = 0.f;
            cur = k;
        }
        if (xT) {
            acc += xT[(size_t)n * 64 + c];  // 256B contiguous per wave
        } else {
            acc += in[(size_t)(n >> 12) * 262144 + c * 4096 + (n & 4095)];
        }
    }
    atomicAdd(&dwT[cur * 64 + c], acc);
}

__global__ void __launch_bounds__(256) ema2_kernel(
    const float* __restrict__ embed_avg, const float* __restrict__ dwT,
    const float* __restrict__ cs_ws, float* __restrict__ out) {
    int i = blockIdx.x * 256 + threadIdx.x;  // i = c*K + k
    int k = i & (K - 1);
    int c = i >> 10;
    float avg = embed_avg[i] * DECAYF + OMDF * dwT[k * 64 + c];
    out[OFF_AVG + i] = avg;
    out[OFF_EMB + i] = avg / cs_ws[k];
}

extern "C" void kernel_launch(void* const* d_in, const int* in_sizes, int n_in,
                              void* d_out, int out_size, void* d_ws, size_t ws_size,
                              hipStream_t stream) {
    const float* in = (const float*)d_in[0];
    const float* E = (const float*)d_in[1];
    const float* cluster_size = (const float*)d_in[2];
    const float* embed_avg = (const float*)d_in[3];
    float* out = (float*)d_out;
    float* ws = (float*)d_ws;

    float* loss = ws;
    float* e2 = ws + 64;
    float* cs = ws + 1088;
    int* cursor = (int*)(ws + 2112);   // 1024
    int* hist = (int*)(ws + 3136);     // 1024
    int* idxi = (int*)(ws + 4224);     // 65536
    unsigned* perm = (unsigned*)(ws + 69760);  // 65536
    unsigned long long* keys = (unsigned long long*)(ws + 135296);  // 65536 u64
    float* dwT = ws + 266368;          // 65536 ([K][64])
    float* ET = ws + 331904;           // 65536 ([K][64])
    float* xT = (ws_size >= (397440ull + 4194304ull) * 4ull) ? (ws + 397440) : nullptr;

    prep_kernel<<<K / 64, 256, 0, stream>>>(E, ET, e2, hist, loss, dwT);
    score_kernel<<<512, 512, 0, stream>>>(in, ET, e2, keys);
    finalize_kernel<<<NPOS / 128, 256, 0, stream>>>(in, ET, e2, keys, out, idxi, xT, loss, hist);
    scan_kernel<<<1, 1024, 0, stream>>>(hist, cluster_size, loss, out, cs, cursor);
    scatter_kernel<<<NPOS / 256, 256, 0, stream>>>(idxi, cursor, perm);
    dw_accum_kernel<<<512, 256, 0, stream>>>(in, xT, perm, dwT);
    ema2_kernel<<<D * K / 256, 256, 0, stream>>>(embed_avg, dwT, cs, out);
}

// Round 8
// 228.316 us; speedup vs baseline: 1.5627x; 1.0609x over previous
//
#include <hip/hip_runtime.h>
#include <float.h>

// VQ-VAE EMA vector quantizer, MI355X (gfx950).
// inputs:  [16,64,64,64] f32 (b,c,h,w) -> N=65536 positions, d=64
// embedding: [64,1024] f32 (d,K)
//
// Lessons: R7  — cooperative grid.sync ~30-40us each; separate launches win.
//          R10 — cross-block ticket + device fences = 9x regression. Never.
//          R13 — bucket skew: per-code work = serial straggler. Balanced
//                32-sorted-entries/wave + dwT atomics only.
//          R14 == R9 (proven 289us total, score 130us @ 8x8 f32 VALU).
//          R17/R19 — bigger f32 tiles = regalloc wall (spill/AGPR tax) ~130us.
//          R21 — MFMA f16 hi/lo + exact-f32 fixup WORKS: score 66us, total
//                242us, absmax == f32 baseline (fixup exact). But MfmaUtil
//                31%, LDS 107KB -> 1 block/CU, barrier-stall ~33%; every
//                block re-converts the same E (600 VALU/lane redundant).
// R22 (this): (a) prep pre-converts E -> frag-linear global Ef16 (Ah|Al
//      interleaved, one coalesced 16B load per (rt,s)); placed in idxi ws
//      region (finalize writes idxi only AFTER score reads Ef16 -> safe).
//      (b) score drops sE LDS: A-frags from L2-resident Ef16; LDS 107->44KB
//      -> 2 blocks/CU; kt-loop has ZERO barriers. (c) finalize fixup:
//      one wave per flagged position, no block barriers.
//      Predict score ~35us (MfmaUtil 50-60%), total ~205us.

#define K 1024
#define D 64
#define NPOS 65536
#define NELEM 4194304
#define DECAYF 0.99f
#define OMDF 0.01f
#define EPSF 1e-5f
#define CCOST 0.25f
#define DELTA 0.004f

#define OFF_Q 0
#define OFF_LOSS 4194304
#define OFF_IDX 4194305
#define OFF_EMB 4259841
#define OFF_NCS 4325377
#define OFF_AVG 4326401

typedef _Float16 half4 __attribute__((ext_vector_type(4)));
typedef float f32x4 __attribute__((ext_vector_type(4)));

// ws float layout:
// [0] loss | [64..1088) e2 | [1088..2112) cs | [2112..3136) cursor(int)
// [3136..4160) hist(int) | [4224..69760) idxi(int) OVERLAID with Ef16
//   (prep writes Ef16; score reads it; finalize then overwrites with idxi)
// [69760..135296) perm(u32) | [135296..266368) keys(u64 x 65536)
// [266368..331904) dwT[K][64] | [331904..397440) ET[K][64]
// [397440..) xT[n][64] (optional, 16 MB)
//
// Ef16 frag-linear layout (halves): block (kt,grt,s) of 512 halves at
//   ((kt*16+grt)*4+s)*512, lane entry = lane*8 + half*4 + j
//   (Ah 4 halves | Al 4 halves = one 16B lane chunk, coalesced).

// Tile-transpose E -> ET[K][64], fused e2, Ef16 fragment build;
// init hist/loss/dwT (no memsets).
__global__ void __launch_bounds__(256) prep_kernel(
    const float* __restrict__ E, float* __restrict__ ET, float* __restrict__ e2,
    _Float16* __restrict__ Ef, int* __restrict__ hist,
    float* __restrict__ loss, float* __restrict__ dwT) {
    __shared__ float tile[64][65];
    __shared__ float part[4][64];
    int tid = threadIdx.x;
    int gid = blockIdx.x * 256 + tid;  // 0..4095
#pragma unroll
    for (int i = 0; i < 16; ++i) dwT[i * 4096 + gid] = 0.f;
    if (gid < K) hist[gid] = 0;
    if (gid == 0) *loss = 0.f;

    int k0 = blockIdx.x * 64;
    int kl = tid & 63;
    int cg_ = tid >> 6;  // 0..3
#pragma unroll
    for (int cc = 0; cc < 16; ++cc) {
        int c = cc * 4 + cg_;
        tile[c][kl] = E[c * K + k0 + kl];  // coalesced
    }
    __syncthreads();
    float s = 0.f;
#pragma unroll
    for (int i = 0; i < 16; ++i) {
        float v = tile[cg_ * 16 + i][kl];
        s = fmaf(v, v, s);
    }
    part[cg_][kl] = s;
#pragma unroll
    for (int i = 0; i < 16; ++i) {
        int w = i * 256 + tid;
        int k = w >> 6, c = w & 63;
        float v = tile[c][k];
        ET[(size_t)(k0 + k) * 64 + c] = v;
        // Ef16 fragment write
        int code = k0 + k;
        int kt = code >> 8, grt = (code >> 4) & 15, l15 = code & 15;
        int ss = c >> 4, g = (c & 15) >> 2, j = c & 3;
        int lane = g * 16 + l15;
        size_t off = (size_t)((kt * 16 + grt) * 4 + ss) * 512 + lane * 8 + j;
        _Float16 h = (_Float16)v;
        Ef[off] = h;
        Ef[off + 4] = (_Float16)(v - (float)h);
    }
    __syncthreads();
    if (tid < 64) e2[k0 + tid] = part[0][tid] + part[1][tid] + part[2][tid] + part[3][tid];
}

__device__ __forceinline__ unsigned mono_f32(float s) {
    unsigned u = __float_as_uint(s);
    return (u & 0x80000000u) ? ~u : (u | 0x80000000u);
}

// R22 MFMA score: 512 thr = 8 waves (wp=pos-half 0..1, wc=code-quarter 0..3).
// Block = 128 pos x all 1024 codes. A-frags stream from global Ef16 (L2);
// x staged once in LDS, converted to persistent B-frags. No loop barriers.
__global__ void __launch_bounds__(512, 4) score_kernel(
    const float* __restrict__ in, const _Float16* __restrict__ Ef,
    const float* __restrict__ e2, unsigned long long* __restrict__ keys) {
    __shared__ __align__(16) float xf[64 * 132];   // [chan][pos 128] padded, 33.8KB
    __shared__ float e2s[1024];
    __shared__ float mgb[128][4];
    __shared__ int   mgi[128][4];
    __shared__ float mgs[128][4];

    int tid = threadIdx.x;
    int lane = tid & 63;
    int w = tid >> 6;
    int wp = w >> 2;   // 0..1
    int wc = w & 3;    // 0..3
    int g = lane >> 4; // 0..3
    int c16 = lane & 15;

    int n0 = blockIdx.x * 128;
    int b = n0 >> 12;
    int r0 = n0 & 4095;

    // stage x f32 tile [64 chan][128 pos]
#pragma unroll
    for (int it = 0; it < 4; ++it) {
        int idx = it * 512 + tid;   // 0..2047
        int c = idx >> 5;
        int q = idx & 31;
        float4 v = *(const float4*)(in + (size_t)b * 262144 + c * 4096 + r0 + q * 4);
        *(float4*)(&xf[c * 132 + q * 4]) = v;
    }
    e2s[tid] = e2[tid];
    e2s[512 + tid] = e2[512 + tid];
    __syncthreads();

    // persistent x fragments (B operand): k=(lane>>4)*4+j+s*16, col=pos
    half4 Bh[4][4], Bl[4][4];   // [pt][s]
#pragma unroll
    for (int pt = 0; pt < 4; ++pt) {
        int p = wp * 64 + pt * 16 + c16;
#pragma unroll
        for (int s = 0; s < 4; ++s) {
            half4 hh, ll;
#pragma unroll
            for (int j = 0; j < 4; ++j) {
                float v = xf[(g * 4 + j + s * 16) * 132 + p];
                _Float16 h = (_Float16)v;
                hh[j] = h;
                ll[j] = (_Float16)(v - (float)h);
            }
            Bh[pt][s] = hh; Bl[pt][s] = ll;
        }
    }

    float best[4], sec[4]; int bk[4];
#pragma unroll
    for (int pt = 0; pt < 4; ++pt) { best[pt] = FLT_MAX; sec[pt] = FLT_MAX; bk[pt] = 0; }

    for (int kt = 0; kt < 4; ++kt) {
#pragma unroll
        for (int rt = 0; rt < 4; ++rt) {
            int grt = wc * 4 + rt;
            f32x4 acc[4];
#pragma unroll
            for (int pt = 0; pt < 4; ++pt) acc[pt] = {0.f, 0.f, 0.f, 0.f};
#pragma unroll
            for (int s = 0; s < 4; ++s) {
                const _Float16* eb = Ef + (size_t)((kt * 16 + grt) * 4 + s) * 512 + lane * 8;
                half4 Ah = *(const half4*)eb;
                half4 Al = *(const half4*)(eb + 4);
#pragma unroll
                for (int pt = 0; pt < 4; ++pt)
                    acc[pt] = __builtin_amdgcn_mfma_f32_16x16x16f16(Ah, Bh[pt][s], acc[pt], 0, 0, 0);
#pragma unroll
                for (int pt = 0; pt < 4; ++pt)
                    acc[pt] = __builtin_amdgcn_mfma_f32_16x16x16f16(Ah, Bl[pt][s], acc[pt], 0, 0, 0);
#pragma unroll
                for (int pt = 0; pt < 4; ++pt)
                    acc[pt] = __builtin_amdgcn_mfma_f32_16x16x16f16(Al, Bh[pt][s], acc[pt], 0, 0, 0);
            }
            int cb = kt * 256 + grt * 16 + g * 4;
#pragma unroll
            for (int r = 0; r < 4; ++r) {
                float ev2 = e2s[cb + r];
                int code = cb + r;
#pragma unroll
                for (int pt = 0; pt < 4; ++pt) {
                    float sc = fmaf(-2.f, acc[pt][r], ev2);
                    if (sc < best[pt]) { sec[pt] = best[pt]; best[pt] = sc; bk[pt] = code; }
                    else sec[pt] = fminf(sec[pt], sc);
                }
            }
        }
    }

    // merge the 4 lane-groups (disjoint code ranges, same pos col)
#pragma unroll
    for (int pt = 0; pt < 4; ++pt) {
#pragma unroll
        for (int m = 16; m <= 32; m <<= 1) {
            float ob = __shfl_xor(best[pt], m);
            int obk = __shfl_xor(bk[pt], m);
            float os = __shfl_xor(sec[pt], m);
            bool take = (ob < best[pt]) || (ob == best[pt] && obk < bk[pt]);
            float ns = take ? fminf(os, best[pt]) : fminf(sec[pt], ob);
            best[pt] = take ? ob : best[pt];
            bk[pt] = take ? obk : bk[pt];
            sec[pt] = ns;
        }
        if (lane < 16) {
            int posl = wp * 64 + pt * 16 + lane;
            mgb[posl][wc] = best[pt]; mgi[posl][wc] = bk[pt]; mgs[posl][wc] = sec[pt];
        }
    }
    __syncthreads();
    if (tid < 128) {
        float bb = mgb[tid][0]; int kw = mgi[tid][0]; float ss = mgs[tid][0];
#pragma unroll
        for (int i = 1; i < 4; ++i) {
            float ob = mgb[tid][i]; int ok = mgi[tid][i]; float os = mgs[tid][i];
            bool take = (ob < bb) || (ob == bb && ok < kw);
            ss = take ? fminf(os, bb) : fminf(ss, ob);
            bb = take ? ob : bb;
            kw = take ? ok : kw;
        }
        unsigned flag = ((ss - bb) < DELTA) ? (1u << 16) : 0u;
        keys[n0 + tid] = ((unsigned long long)mono_f32(bb) << 32) | (unsigned)kw | flag;
    }
}

// finalize: fixup flagged positions (exact f32 argmin, one WAVE per position,
// no block barriers), then 4 pos x 8 chan per thread: q gather, loss, hist.
__global__ void __launch_bounds__(256) finalize_kernel(
    const float* __restrict__ in, const float* __restrict__ ET,
    const float* __restrict__ e2, const unsigned long long* __restrict__ keys,
    float* __restrict__ out, int* __restrict__ idxi, float* __restrict__ xT,
    float* __restrict__ loss, int* __restrict__ hist) {
    __shared__ int s_kk[128];
    __shared__ int s_fl[128];
    __shared__ int s_nf;
    __shared__ float s_x4[4][64];

    int tid = threadIdx.x;
    if (tid == 0) s_nf = 0;
    __syncthreads();
    if (tid < 128) {
        unsigned long long key = keys[blockIdx.x * 128 + tid];
        s_kk[tid] = (int)(key & 0x3FFull);
        if (key & (1ull << 16)) {
            int sl = atomicAdd(&s_nf, 1);
            s_fl[sl] = tid;
        }
    }
    __syncthreads();
    int nf = s_nf;
    {
        int wv = tid >> 6, ln = tid & 63;
        for (int f0 = 0; f0 < nf; f0 += 4) {
            int f = f0 + wv;
            if (f < nf) {
                int posl = s_fl[f];
                int n = blockIdx.x * 128 + posl;
                s_x4[wv][ln] = in[(size_t)(n >> 12) * 262144 + ln * 4096 + (n & 4095)];
                unsigned long long bkey = ~0ull;
                for (int i = 0; i < 16; ++i) {
                    int c = ln + i * 64;
                    const float* ep = ET + (size_t)c * 64;
                    float dot = 0.f;
#pragma unroll
                    for (int j = 0; j < 64; ++j) dot = fmaf(s_x4[wv][j], ep[j], dot);
                    float sc = fmaf(-2.f, dot, e2[c]);
                    unsigned long long kq = ((unsigned long long)mono_f32(sc) << 32) | (unsigned)c;
                    if (kq < bkey) bkey = kq;
                }
#pragma unroll
                for (int off = 32; off > 0; off >>= 1) {
                    unsigned long long o = __shfl_down(bkey, off);
                    if (o < bkey) bkey = o;
                }
                if (ln == 0) s_kk[posl] = (int)(bkey & 0x3FFull);
            }
        }
    }
    __syncthreads();

    int pg = tid & 31;
    int ch8 = tid >> 5;  // 0..7
    int np = blockIdx.x * 128 + pg * 4;
    int b = np >> 12, r = np & 4095;
    int c0 = ch8 * 8;
    const float* inb = in + (size_t)b * 262144 + r;
    float* qb = out + OFF_Q + (size_t)b * 262144 + r;

    int kk[4];
#pragma unroll
    for (int p = 0; p < 4; ++p) kk[p] = s_kk[pg * 4 + p];

    float4 xv[8];
#pragma unroll
    for (int i = 0; i < 8; ++i) xv[i] = *(const float4*)(inb + (c0 + i) * 4096);

    float4 e0[4], e1[4];
#pragma unroll
    for (int p = 0; p < 4; ++p) {
        const float* ep = ET + (size_t)kk[p] * 64 + c0;
        e0[p] = *(const float4*)ep;
        e1[p] = *(const float4*)(ep + 4);
    }

#define ECOMP(p, i) ((i) < 4 ? ((const float*)&e0[p])[(i)] : ((const float*)&e1[p])[(i) - 4])
#define XCOMP(i, p) ((p) == 0 ? xv[i].x : (p) == 1 ? xv[i].y : (p) == 2 ? xv[i].z : xv[i].w)

    float sq = 0.f;
#pragma unroll
    for (int i = 0; i < 8; ++i) {
        float4 qv = make_float4(ECOMP(0, i), ECOMP(1, i), ECOMP(2, i), ECOMP(3, i));
        *(float4*)(qb + (c0 + i) * 4096) = qv;
        float d0 = qv.x - xv[i].x, d1 = qv.y - xv[i].y;
        float d2 = qv.z - xv[i].z, d3 = qv.w - xv[i].w;
        sq = fmaf(d0, d0, sq); sq = fmaf(d1, d1, sq);
        sq = fmaf(d2, d2, sq); sq = fmaf(d3, d3, sq);
    }

    if (xT) {
#pragma unroll
        for (int p = 0; p < 4; ++p) {
            float* xp = xT + (size_t)(np + p) * 64 + c0;
            *(float4*)xp = make_float4(XCOMP(0, p), XCOMP(1, p), XCOMP(2, p), XCOMP(3, p));
            *(float4*)(xp + 4) = make_float4(XCOMP(4, p), XCOMP(5, p), XCOMP(6, p), XCOMP(7, p));
        }
    }

    if (ch8 == 0) {
#pragma unroll
        for (int p = 0; p < 4; ++p) out[OFF_IDX + np + p] = (float)kk[p];
        *(int4*)(idxi + np) = make_int4(kk[0], kk[1], kk[2], kk[3]);
#pragma unroll
        for (int p = 0; p < 4; ++p) atomicAdd(&hist[kk[p]], 1);
    }

#pragma unroll
    for (int off = 32; off > 0; off >>= 1) sq += __shfl_down(sq, off);
    if ((tid & 63) == 0) atomicAdd(loss, sq);
}

// One block: exclusive scan of hist + EMA stage1.
__global__ void __launch_bounds__(1024) scan_kernel(
    const int* __restrict__ hist, const float* __restrict__ cluster_size,
    const float* __restrict__ loss, float* __restrict__ out,
    float* __restrict__ cs_ws, int* __restrict__ cursor) {
    int t = threadIdx.x;
    __shared__ int sc[1024];
    __shared__ float fred[1024];
    int cnt = hist[t];
    sc[t] = cnt;
    __syncthreads();
    for (int off = 1; off < 1024; off <<= 1) {
        int v = (t >= off) ? sc[t - off] : 0;
        __syncthreads();
        sc[t] += v;
        __syncthreads();
    }
    cursor[t] = sc[t] - cnt;

    float ncs = cluster_size[t] * DECAYF + OMDF * (float)cnt;
    fred[t] = ncs;
    __syncthreads();
    for (int s = 512; s > 0; s >>= 1) {
        if (t < s) fred[t] += fred[t + s];
        __syncthreads();
    }
    float nsum = fred[0];
    out[OFF_NCS + t] = ncs;
    cs_ws[t] = (ncs + EPSF) / (nsum + 1024.f * EPSF) * nsum;
    if (t == 0) out[OFF_LOSS] = CCOST * loss[0] / (float)NELEM;
}

__global__ void __launch_bounds__(256) scatter_kernel(
    const int* __restrict__ idxi, int* __restrict__ cursor,
    unsigned* __restrict__ perm) {
    int n = blockIdx.x * 256 + threadIdx.x;
    int k = idxi[n];
    int slot = atomicAdd(&cursor[k], 1);
    perm[slot] = ((unsigned)k << 17) | (unsigned)n;  // k:10b, n:17b
}

// Balanced segmented reduction over sorted perm; wave = 32 entries.
__global__ void __launch_bounds__(256) dw_accum_kernel(
    const float* __restrict__ in, const float* __restrict__ xT,
    const unsigned* __restrict__ perm, float* __restrict__ dwT) {
    int t = threadIdx.x;
    int c = t & 63;
    int wv = t >> 6;
    int base = (blockIdx.x * 4 + wv) * 32;  // 2048 waves x 32 = 65536

    __shared__ unsigned spm[4][32];
    if (c < 32) spm[wv][c] = perm[base + c];
    __syncthreads();

    float acc = 0.f;
    unsigned cur = spm[wv][0] >> 17;
#pragma unroll 4
    for (int i = 0; i < 32; ++i) {
        unsigned e = spm[wv][i];  // broadcast
        unsigned k = e >> 17;
        unsigned n = e & 0x1FFFFu;
        if (k != cur) {  // wave-uniform
            atomicAdd(&dwT[cur * 64 + c], acc);
            acc = 0.f;
            cur = k;
        }
        if (xT) {
            acc += xT[(size_t)n * 64 + c];  // 256B contiguous per wave
        } else {
            acc += in[(size_t)(n >> 12) * 262144 + c * 4096 + (n & 4095)];
        }
    }
    atomicAdd(&dwT[cur * 64 + c], acc);
}

__global__ void __launch_bounds__(256) ema2_kernel(
    const float* __restrict__ embed_avg, const float* __restrict__ dwT,
    const float* __restrict__ cs_ws, float* __restrict__ out) {
    int i = blockIdx.x * 256 + threadIdx.x;  // i = c*K + k
    int k = i & (K - 1);
    int c = i >> 10;
    float avg = embed_avg[i] * DECAYF + OMDF * dwT[k * 64 + c];
    out[OFF_AVG + i] = avg;
    out[OFF_EMB + i] = avg / cs_ws[k];
}

extern "C" void kernel_launch(void* const* d_in, const int* in_sizes, int n_in,
                              void* d_out, int out_size, void* d_ws, size_t ws_size,
                              hipStream_t stream) {
    const float* in = (const float*)d_in[0];
    const float* E = (const float*)d_in[1];
    const float* cluster_size = (const float*)d_in[2];
    const float* embed_avg = (const float*)d_in[3];
    float* out = (float*)d_out;
    float* ws = (float*)d_ws;

    float* loss = ws;
    float* e2 = ws + 64;
    float* cs = ws + 1088;
    int* cursor = (int*)(ws + 2112);   // 1024
    int* hist = (int*)(ws + 3136);     // 1024
    int* idxi = (int*)(ws + 4224);     // 65536 (reused: Ef16 before finalize)
    _Float16* Ef = (_Float16*)(ws + 4224);     // 131072 halves = same 256KB
    unsigned* perm = (unsigned*)(ws + 69760);  // 65536
    unsigned long long* keys = (unsigned long long*)(ws + 135296);  // 65536 u64
    float* dwT = ws + 266368;          // 65536 ([K][64])
    float* ET = ws + 331904;           // 65536 ([K][64])
    float* xT = (ws_size >= (397440ull + 4194304ull) * 4ull) ? (ws + 397440) : nullptr;

    prep_kernel<<<K / 64, 256, 0, stream>>>(E, ET, e2, Ef, hist, loss, dwT);
    score_kernel<<<512, 512, 0, stream>>>(in, Ef, e2, keys);
    finalize_kernel<<<NPOS / 128, 256, 0, stream>>>(in, ET, e2, keys, out, idxi, xT, loss, hist);
    scan_kernel<<<1, 1024, 0, stream>>>(hist, cluster_size, loss, out, cs, cursor);
    scatter_kernel<<<NPOS / 256, 256, 0, stream>>>(idxi, cursor, perm);
    dw_accum_kernel<<<512, 256, 0, stream>>>(in, xT, perm, dwT);
    ema2_kernel<<<D * K / 256, 256, 0, stream>>>(embed_avg, dwT, cs, out);
}

// Round 9
// 226.055 us; speedup vs baseline: 1.5784x; 1.0100x over previous
//
#include <hip/hip_runtime.h>
#include <float.h>

// VQ-VAE EMA vector quantizer, MI355X (gfx950).
// inputs:  [16,64,64,64] f32 (b,c,h,w) -> N=65536 positions, d=64
// embedding: [64,1024] f32 (d,K)
//
// Lessons: R7  — cooperative grid.sync ~30-40us each; separate launches win.
//          R10 — cross-block ticket + device fences = 9x regression. Never.
//          R13 — bucket skew: per-code work = serial straggler. Balanced
//                32-sorted-entries/wave + dwT atomics only.
//          R14 — proven f32 baseline 289us (score 130us, regalloc-walled).
//          R21 — MFMA f16 hi/lo + exact-f32 fixup: score 66us, total 242.
//          R22 — prep-built frag-linear Ef16 (L2) + barrier-free kt-loop:
//                total 228. New bottleneck: finalize 59us at 12% BW,
//                VALUBusy 1.5%, Occupancy 8.7% — latency-bound, 8x over
//                its 7.6us BW floor.
// R23 (this): FUSE finalize into score's epilogue. Score already has the
//      x-tile in LDS (f32) + per-position winners in-register. Epilogue:
//      in-block exact-f32 fixup (same sequential-fmaf dot as R22), then
//      q gather-write, loss, hist, idx, idxi, xT — all from LDS/L2.
//      Eliminates: 59us dispatch, keys round-trip, 16MB in re-read.
//      keys ws region freed -> Ef16 moves there (no idxi overlay).
//      6 dispatches. Predict score ~50-65us (WRITE ~33MB), total ~185.

#define K 1024
#define D 64
#define NPOS 65536
#define NELEM 4194304
#define DECAYF 0.99f
#define OMDF 0.01f
#define EPSF 1e-5f
#define CCOST 0.25f
#define DELTA 0.004f

#define OFF_Q 0
#define OFF_LOSS 4194304
#define OFF_IDX 4194305
#define OFF_EMB 4259841
#define OFF_NCS 4325377
#define OFF_AVG 4326401

typedef _Float16 half4 __attribute__((ext_vector_type(4)));
typedef float f32x4 __attribute__((ext_vector_type(4)));

// ws float layout:
// [0] loss | [64..1088) e2 | [1088..2112) cs | [2112..3136) cursor(int)
// [3136..4160) hist(int) | [4224..69760) idxi(int)
// [69760..135296) perm(u32)
// [135296..266368) Ef16 region (131072 halves = 256KB; old keys slot)
// [266368..331904) dwT[K][64] | [331904..397440) ET[K][64]
// [397440..) xT[n][64] (optional, 16 MB)
//
// Ef16 frag-linear layout (halves): block (kt,grt,s) of 512 halves at
//   ((kt*16+grt)*4+s)*512, lane entry = lane*8 + half*4 + j
//   (Ah 4 halves | Al 4 halves = one 16B lane chunk, coalesced).

// Tile-transpose E -> ET[K][64], fused e2, Ef16 fragment build;
// init hist/loss/dwT (no memsets).
__global__ void __launch_bounds__(256) prep_kernel(
    const float* __restrict__ E, float* __restrict__ ET, float* __restrict__ e2,
    _Float16* __restrict__ Ef, int* __restrict__ hist,
    float* __restrict__ loss, float* __restrict__ dwT) {
    __shared__ float tile[64][65];
    __shared__ float part[4][64];
    int tid = threadIdx.x;
    int gid = blockIdx.x * 256 + tid;  // 0..4095
#pragma unroll
    for (int i = 0; i < 16; ++i) dwT[i * 4096 + gid] = 0.f;
    if (gid < K) hist[gid] = 0;
    if (gid == 0) *loss = 0.f;

    int k0 = blockIdx.x * 64;
    int kl = tid & 63;
    int cg_ = tid >> 6;  // 0..3
#pragma unroll
    for (int cc = 0; cc < 16; ++cc) {
        int c = cc * 4 + cg_;
        tile[c][kl] = E[c * K + k0 + kl];  // coalesced
    }
    __syncthreads();
    float s = 0.f;
#pragma unroll
    for (int i = 0; i < 16; ++i) {
        float v = tile[cg_ * 16 + i][kl];
        s = fmaf(v, v, s);
    }
    part[cg_][kl] = s;
#pragma unroll
    for (int i = 0; i < 16; ++i) {
        int w = i * 256 + tid;
        int k = w >> 6, c = w & 63;
        float v = tile[c][k];
        ET[(size_t)(k0 + k) * 64 + c] = v;
        // Ef16 fragment write
        int code = k0 + k;
        int kt = code >> 8, grt = (code >> 4) & 15, l15 = code & 15;
        int ss = c >> 4, g = (c & 15) >> 2, j = c & 3;
        int lane = g * 16 + l15;
        size_t off = (size_t)((kt * 16 + grt) * 4 + ss) * 512 + lane * 8 + j;
        _Float16 h = (_Float16)v;
        Ef[off] = h;
        Ef[off + 4] = (_Float16)(v - (float)h);
    }
    __syncthreads();
    if (tid < 64) e2[k0 + tid] = part[0][tid] + part[1][tid] + part[2][tid] + part[3][tid];
}

__device__ __forceinline__ unsigned mono_f32(float s) {
    unsigned u = __float_as_uint(s);
    return (u & 0x80000000u) ? ~u : (u | 0x80000000u);
}

// R23 fused score+finalize: 512 thr = 8 waves (wp 0..1, wc 0..3).
// Block = 128 pos x all 1024 codes. A-frags from L2-resident Ef16;
// x staged once in LDS (f32, reused by epilogue). MFMA kt-loop barrier-free.
// Epilogue: exact-f32 fixup for flagged, then q/loss/hist/idx/idxi/xT.
__global__ void __launch_bounds__(512, 2) score_kernel(
    const float* __restrict__ in, const _Float16* __restrict__ Ef,
    const float* __restrict__ ET, const float* __restrict__ e2,
    float* __restrict__ out, int* __restrict__ idxi, float* __restrict__ xT,
    float* __restrict__ loss, int* __restrict__ hist) {
    __shared__ __align__(16) float xf[64 * 132];   // [chan][pos 128] padded, 33.8KB
    __shared__ float e2s[1024];
    __shared__ float mgb[128][4];
    __shared__ int   mgi[128][4];
    __shared__ float mgs[128][4];
    __shared__ int s_kk[128];
    __shared__ int s_fl[128];
    __shared__ int s_nf;

    int tid = threadIdx.x;
    int lane = tid & 63;
    int w = tid >> 6;
    int wp = w >> 2;   // 0..1
    int wc = w & 3;    // 0..3
    int g = lane >> 4; // 0..3
    int c16 = lane & 15;

    int n0 = blockIdx.x * 128;
    int b = n0 >> 12;
    int r0 = n0 & 4095;

    if (tid == 0) s_nf = 0;

    // stage x f32 tile [64 chan][128 pos]
#pragma unroll
    for (int it = 0; it < 4; ++it) {
        int idx = it * 512 + tid;   // 0..2047
        int c = idx >> 5;
        int q = idx & 31;
        float4 v = *(const float4*)(in + (size_t)b * 262144 + c * 4096 + r0 + q * 4);
        *(float4*)(&xf[c * 132 + q * 4]) = v;
    }
    e2s[tid] = e2[tid];
    e2s[512 + tid] = e2[512 + tid];
    __syncthreads();

    // persistent x fragments (B operand): k=(lane>>4)*4+j+s*16, col=pos
    half4 Bh[4][4], Bl[4][4];   // [pt][s]
#pragma unroll
    for (int pt = 0; pt < 4; ++pt) {
        int p = wp * 64 + pt * 16 + c16;
#pragma unroll
        for (int s = 0; s < 4; ++s) {
            half4 hh, ll;
#pragma unroll
            for (int j = 0; j < 4; ++j) {
                float v = xf[(g * 4 + j + s * 16) * 132 + p];
                _Float16 h = (_Float16)v;
                hh[j] = h;
                ll[j] = (_Float16)(v - (float)h);
            }
            Bh[pt][s] = hh; Bl[pt][s] = ll;
        }
    }

    float best[4], sec[4]; int bk[4];
#pragma unroll
    for (int pt = 0; pt < 4; ++pt) { best[pt] = FLT_MAX; sec[pt] = FLT_MAX; bk[pt] = 0; }

    for (int kt = 0; kt < 4; ++kt) {
#pragma unroll
        for (int rt = 0; rt < 4; ++rt) {
            int grt = wc * 4 + rt;
            f32x4 acc[4];
#pragma unroll
            for (int pt = 0; pt < 4; ++pt) acc[pt] = {0.f, 0.f, 0.f, 0.f};
#pragma unroll
            for (int s = 0; s < 4; ++s) {
                const _Float16* eb = Ef + (size_t)((kt * 16 + grt) * 4 + s) * 512 + lane * 8;
                half4 Ah = *(const half4*)eb;
                half4 Al = *(const half4*)(eb + 4);
#pragma unroll
                for (int pt = 0; pt < 4; ++pt)
                    acc[pt] = __builtin_amdgcn_mfma_f32_16x16x16f16(Ah, Bh[pt][s], acc[pt], 0, 0, 0);
#pragma unroll
                for (int pt = 0; pt < 4; ++pt)
                    acc[pt] = __builtin_amdgcn_mfma_f32_16x16x16f16(Ah, Bl[pt][s], acc[pt], 0, 0, 0);
#pragma unroll
                for (int pt = 0; pt < 4; ++pt)
                    acc[pt] = __builtin_amdgcn_mfma_f32_16x16x16f16(Al, Bh[pt][s], acc[pt], 0, 0, 0);
            }
            int cb = kt * 256 + grt * 16 + g * 4;
#pragma unroll
            for (int r = 0; r < 4; ++r) {
                float ev2 = e2s[cb + r];
                int code = cb + r;
#pragma unroll
                for (int pt = 0; pt < 4; ++pt) {
                    float sc = fmaf(-2.f, acc[pt][r], ev2);
                    if (sc < best[pt]) { sec[pt] = best[pt]; best[pt] = sc; bk[pt] = code; }
                    else sec[pt] = fminf(sec[pt], sc);
                }
            }
        }
    }

    // merge the 4 lane-groups (disjoint code ranges, same pos col)
#pragma unroll
    for (int pt = 0; pt < 4; ++pt) {
#pragma unroll
        for (int m = 16; m <= 32; m <<= 1) {
            float ob = __shfl_xor(best[pt], m);
            int obk = __shfl_xor(bk[pt], m);
            float os = __shfl_xor(sec[pt], m);
            bool take = (ob < best[pt]) || (ob == best[pt] && obk < bk[pt]);
            float ns = take ? fminf(os, best[pt]) : fminf(sec[pt], ob);
            best[pt] = take ? ob : best[pt];
            bk[pt] = take ? obk : bk[pt];
            sec[pt] = ns;
        }
        if (lane < 16) {
            int posl = wp * 64 + pt * 16 + lane;
            mgb[posl][wc] = best[pt]; mgi[posl][wc] = bk[pt]; mgs[posl][wc] = sec[pt];
        }
    }
    __syncthreads();
    if (tid < 128) {
        float bb = mgb[tid][0]; int kw = mgi[tid][0]; float ss = mgs[tid][0];
#pragma unroll
        for (int i = 1; i < 4; ++i) {
            float ob = mgb[tid][i]; int ok = mgi[tid][i]; float os = mgs[tid][i];
            bool take = (ob < bb) || (ob == bb && ok < kw);
            ss = take ? fminf(os, bb) : fminf(ss, ob);
            bb = take ? ob : bb;
            kw = take ? ok : kw;
        }
        s_kk[tid] = kw;
        if ((ss - bb) < DELTA) {
            int sl = atomicAdd(&s_nf, 1);
            s_fl[sl] = tid;
        }
    }
    __syncthreads();

    // fixup: exact f32 argmin for flagged positions; one wave per position.
    // Sequential-fmaf dot — IDENTICAL rounding to R22's fixup (proven).
    int nf = s_nf;
    for (int f0 = 0; f0 < nf; f0 += 8) {
        int f = f0 + w;
        if (f < nf) {
            int posl = s_fl[f];
            unsigned long long bkey = ~0ull;
            for (int i = 0; i < 16; ++i) {
                int c = lane + i * 64;
                const float* ep = ET + (size_t)c * 64;
                float dot = 0.f;
#pragma unroll
                for (int j = 0; j < 64; ++j) dot = fmaf(xf[j * 132 + posl], ep[j], dot);
                float sc = fmaf(-2.f, dot, e2s[c]);
                unsigned long long kq = ((unsigned long long)mono_f32(sc) << 32) | (unsigned)c;
                if (kq < bkey) bkey = kq;
            }
#pragma unroll
            for (int off = 32; off > 0; off >>= 1) {
                unsigned long long o = __shfl_down(bkey, off);
                if (o < bkey) bkey = o;
            }
            if (lane == 0) s_kk[posl] = (int)(bkey & 0x3FFull);
        }
    }
    __syncthreads();

    // epilogue: 512 thr = 32 pos-groups (4 pos) x 16 chan-groups (4 chan)
    {
        int pg = tid & 31;
        int ch4 = tid >> 5;       // 0..15
        int c0 = ch4 * 4;
        int p4 = pg * 4;
        int np = n0 + p4;

        int kk[4];
#pragma unroll
        for (int p = 0; p < 4; ++p) kk[p] = s_kk[p4 + p];

        float4 xv4[4];
#pragma unroll
        for (int c = 0; c < 4; ++c) xv4[c] = *(float4*)&xf[(c0 + c) * 132 + p4];

        float4 eg[4];
#pragma unroll
        for (int p = 0; p < 4; ++p) eg[p] = *(const float4*)(ET + (size_t)kk[p] * 64 + c0);

        float* qb = out + OFF_Q + (size_t)b * 262144 + r0;
        float sq = 0.f;
#pragma unroll
        for (int c = 0; c < 4; ++c) {
            float4 qv = make_float4(((const float*)&eg[0])[c], ((const float*)&eg[1])[c],
                                    ((const float*)&eg[2])[c], ((const float*)&eg[3])[c]);
            *(float4*)(qb + (c0 + c) * 4096 + p4) = qv;
            float d0 = qv.x - ((const float*)&xv4[c])[0];
            float d1 = qv.y - ((const float*)&xv4[c])[1];
            float d2 = qv.z - ((const float*)&xv4[c])[2];
            float d3 = qv.w - ((const float*)&xv4[c])[3];
            sq = fmaf(d0, d0, sq); sq = fmaf(d1, d1, sq);
            sq = fmaf(d2, d2, sq); sq = fmaf(d3, d3, sq);
        }

        if (xT) {
#pragma unroll
            for (int p = 0; p < 4; ++p) {
                float4 tv = make_float4(((const float*)&xv4[0])[p], ((const float*)&xv4[1])[p],
                                        ((const float*)&xv4[2])[p], ((const float*)&xv4[3])[p]);
                *(float4*)(xT + (size_t)(np + p) * 64 + c0) = tv;
            }
        }

        if (ch4 == 0) {
#pragma unroll
            for (int p = 0; p < 4; ++p) out[OFF_IDX + np + p] = (float)kk[p];
            *(int4*)(idxi + np) = make_int4(kk[0], kk[1], kk[2], kk[3]);
#pragma unroll
            for (int p = 0; p < 4; ++p) atomicAdd(&hist[kk[p]], 1);
        }

#pragma unroll
        for (int off = 32; off > 0; off >>= 1) sq += __shfl_down(sq, off);
        if (lane == 0) atomicAdd(loss, sq);
    }
}

// One block: exclusive scan of hist + EMA stage1.
__global__ void __launch_bounds__(1024) scan_kernel(
    const int* __restrict__ hist, const float* __restrict__ cluster_size,
    const float* __restrict__ loss, float* __restrict__ out,
    float* __restrict__ cs_ws, int* __restrict__ cursor) {
    int t = threadIdx.x;
    __shared__ int sc[1024];
    __shared__ float fred[1024];
    int cnt = hist[t];
    sc[t] = cnt;
    __syncthreads();
    for (int off = 1; off < 1024; off <<= 1) {
        int v = (t >= off) ? sc[t - off] : 0;
        __syncthreads();
        sc[t] += v;
        __syncthreads();
    }
    cursor[t] = sc[t] - cnt;

    float ncs = cluster_size[t] * DECAYF + OMDF * (float)cnt;
    fred[t] = ncs;
    __syncthreads();
    for (int s = 512; s > 0; s >>= 1) {
        if (t < s) fred[t] += fred[t + s];
        __syncthreads();
    }
    float nsum = fred[0];
    out[OFF_NCS + t] = ncs;
    cs_ws[t] = (ncs + EPSF) / (nsum + 1024.f * EPSF) * nsum;
    if (t == 0) out[OFF_LOSS] = CCOST * loss[0] / (float)NELEM;
}

__global__ void __launch_bounds__(256) scatter_kernel(
    const int* __restrict__ idxi, int* __restrict__ cursor,
    unsigned* __restrict__ perm) {
    int n = blockIdx.x * 256 + threadIdx.x;
    int k = idxi[n];
    int slot = atomicAdd(&cursor[k], 1);
    perm[slot] = ((unsigned)k << 17) | (unsigned)n;  // k:10b, n:17b
}

// Balanced segmented reduction over sorted perm; wave = 32 entries.
__global__ void __launch_bounds__(256) dw_accum_kernel(
    const float* __restrict__ in, const float* __restrict__ xT,
    const unsigned* __restrict__ perm, float* __restrict__ dwT) {
    int t = threadIdx.x;
    int c = t & 63;
    int wv = t >> 6;
    int base = (blockIdx.x * 4 + wv) * 32;  // 2048 waves x 32 = 65536

    __shared__ unsigned spm[4][32];
    if (c < 32) spm[wv][c] = perm[base + c];
    __syncthreads();

    float acc = 0.f;
    unsigned cur = spm[wv][0] >> 17;
#pragma unroll 4
    for (int i = 0; i < 32; ++i) {
        unsigned e = spm[wv][i];  // broadcast
        unsigned k = e >> 17;
        unsigned n = e & 0x1FFFFu;
        if (k != cur) {  // wave-uniform
            atomicAdd(&dwT[cur * 64 + c], acc);
            acc = 0.f;
            cur = k;
        }
        if (xT) {
            acc += xT[(size_t)n * 64 + c];  // 256B contiguous per wave
        } else {
            acc += in[(size_t)(n >> 12) * 262144 + c * 4096 + (n & 4095)];
        }
    }
    atomicAdd(&dwT[cur * 64 + c], acc);
}

__global__ void __launch_bounds__(256) ema2_kernel(
    const float* __restrict__ embed_avg, const float* __restrict__ dwT,
    const float* __restrict__ cs_ws, float* __restrict__ out) {
    int i = blockIdx.x * 256 + threadIdx.x;  // i = c*K + k
    int k = i & (K - 1);
    int c = i >> 10;
    float avg = embed_avg[i] * DECAYF + OMDF * dwT[k * 64 + c];
    out[OFF_AVG + i] = avg;
    out[OFF_EMB + i] = avg / cs_ws[k];
}

extern "C" void kernel_launch(void* const* d_in, const int* in_sizes, int n_in,
                              void* d_out, int out_size, void* d_ws, size_t ws_size,
                              hipStream_t stream) {
    const float* in = (const float*)d_in[0];
    const float* E = (const float*)d_in[1];
    const float* cluster_size = (const float*)d_in[2];
    const float* embed_avg = (const float*)d_in[3];
    float* out = (float*)d_out;
    float* ws = (float*)d_ws;

    float* loss = ws;
    float* e2 = ws + 64;
    float* cs = ws + 1088;
    int* cursor = (int*)(ws + 2112);   // 1024
    int* hist = (int*)(ws + 3136);     // 1024
    int* idxi = (int*)(ws + 4224);     // 65536
    unsigned* perm = (unsigned*)(ws + 69760);  // 65536
    _Float16* Ef = (_Float16*)(ws + 135296);   // 131072 halves (old keys slot)
    float* dwT = ws + 266368;          // 65536 ([K][64])
    float* ET = ws + 331904;           // 65536 ([K][64])
    float* xT = (ws_size >= (397440ull + 4194304ull) * 4ull) ? (ws + 397440) : nullptr;

    prep_kernel<<<K / 64, 256, 0, stream>>>(E, ET, e2, Ef, hist, loss, dwT);
    score_kernel<<<512, 512, 0, stream>>>(in, Ef, ET, e2, out, idxi, xT, loss, hist);
    scan_kernel<<<1, 1024, 0, stream>>>(hist, cluster_size, loss, out, cs, cursor);
    scatter_kernel<<<NPOS / 256, 256, 0, stream>>>(idxi, cursor, perm);
    dw_accum_kernel<<<512, 256, 0, stream>>>(in, xT, perm, dwT);
    ema2_kernel<<<D * K / 256, 256, 0, stream>>>(embed_avg, dwT, cs, out);
}